// Round 12
// baseline (4653.106 us; speedup 1.0000x reference)
//
#include <hip/hip_runtime.h>
#include <hip/hip_bf16.h>

#define DD 4096
#define NTOK 8192

using u16 = unsigned short;

typedef __attribute__((ext_vector_type(8))) short bfrag;   // 8 bf16 = 4 VGPR
typedef __attribute__((ext_vector_type(4))) float ffrag;   // 16x16 MFMA C/D
typedef __attribute__((ext_vector_type(4))) float f32x4v;

// RNE float -> bf16 (bit math; matches numpy/JAX round-to-nearest-even)
__device__ __forceinline__ u16 f2bf(float f) {
  unsigned u = __float_as_uint(f);
  u += 0x7FFFu + ((u >> 16) & 1u);
  return (u16)(u >> 16);
}
__device__ __forceinline__ float bf2f(u16 u) {
  return __uint_as_float(((unsigned)u) << 16);
}

#define GLDS16(g, l)                                                  \
  __builtin_amdgcn_global_load_lds(                                   \
      (__attribute__((address_space(1))) const void*)(g),             \
      (__attribute__((address_space(3))) void*)(l), 16, 0, 0)

#define MEMFENCE() asm volatile("" ::: "memory")

// ---------------- split x: f32 -> (bf16 hi, bf16 lo) ----------------
__global__ void __launch_bounds__(256) split_bf16_kernel(
    const float* __restrict__ in, u16* __restrict__ hi,
    u16* __restrict__ lo, long n4) {
  long i = (long)blockIdx.x * blockDim.x + threadIdx.x;
  const long stride = (long)gridDim.x * blockDim.x;
  for (; i < n4; i += stride) {
    f32x4v v = reinterpret_cast<const f32x4v*>(in)[i];
    u16 h[4], l[4];
#pragma unroll
    for (int j = 0; j < 4; ++j) {
      float f = v[j];
      u16 hb = f2bf(f);
      h[j] = hb;
      l[j] = f2bf(f - bf2f(hb));
    }
    ushort4 hv, lv;
    hv.x = h[0]; hv.y = h[1]; hv.z = h[2]; hv.w = h[3];
    lv.x = l[0]; lv.y = l[1]; lv.z = l[2]; lv.w = l[3];
    reinterpret_cast<ushort4*>(hi)[i] = hv;
    reinterpret_cast<ushort4*>(lo)[i] = lv;
  }
}

// ------ fused Pi prep: f32 Pi -> p_hi, p_lo (row-major) + piT (bf16 Pi^T)
__global__ void __launch_bounds__(256) prep_pi_fused_kernel(
    const float* __restrict__ in, u16* __restrict__ hi,
    u16* __restrict__ lo, u16* __restrict__ piT) {
  __shared__ u16 tile[64][65];
  const int bc = blockIdx.x << 6;
  const int br = blockIdx.y << 6;
  const int tc = threadIdx.x & 63;
  const int tr0 = threadIdx.x >> 6;
#pragma unroll
  for (int p = 0; p < 16; ++p) {
    int r = tr0 + (p << 2);
    float f = in[(size_t)(br + r) * DD + (bc + tc)];
    u16 hb = f2bf(f);
    hi[(size_t)(br + r) * DD + (bc + tc)] = hb;
    lo[(size_t)(br + r) * DD + (bc + tc)] = f2bf(f - bf2f(hb));
    tile[tc][r] = hb;
  }
  __syncthreads();
#pragma unroll
  for (int p = 0; p < 16; ++p) {
    int orow = tr0 + (p << 2);
    piT[(size_t)(bc + orow) * DD + (br + tc)] = tile[orow][tc];
  }
}

// ============ FUSED 3-term GEMM1 (R10 schedule, now 3 blocks/CU):
//   yq = quant( xh@ph^T + xl@ph^T + xh@pl^T )
// Tile 256x128, 4 waves (2Mx2N), per-wave 128x64. LDS single-buffered 48KB
// -> 3 blocks/CU (3 x 48.5KB = 145.5KB <= 160KB; VGPR 116 <= 170).
// 5 phases/tile; staging after lgkm-drain of each region's last read;
// counted RAW waits P3-end vmcnt(10), tile-end vmcnt(2). Only change vs
// the R10 known-good kernel: __launch_bounds__(256,3) for occupancy.
__global__ void __launch_bounds__(256, 3) gemm_fused3_kernel(
    const u16* __restrict__ Ah_, const u16* __restrict__ Al_,
    const u16* __restrict__ Bh_, const u16* __restrict__ Bl_,
    u16* __restrict__ Yq, const float* __restrict__ cent, int M, int N) {
  __shared__ __align__(16) char SM[49152];
  __shared__ float clut[16];
  const int tid = threadIdx.x;
  if (tid < 16) clut[tid] = cent[tid];

  // XCD swizzle (nwg=1024, %8==0 -> bijective)
  const int nbn = N >> 7;                 // 32
  const int nwg = (M >> 8) * nbn;         // 1024
  int wg = blockIdx.x;
  wg = (wg & 7) * (nwg >> 3) + (wg >> 3);
  const int tm = (wg / nbn) << 8;
  const int tn = (wg % nbn) << 7;

  const int lane = tid & 63;
  const int wv = tid >> 6;   // 0..3
  const int wm = wv >> 1;    // 0..1 (128-row panel)
  const int wn = wv & 1;     // 0..1 (64-col panel)
  const int l15 = lane & 15;
  const int kslc = lane >> 4;

  // staging: dest linear, source pre-unswizzled (involution)
  const int key = (tid >> 3) & 7;
  const int baseL = (tid * 16) ^ (key << 4);
  const int srow = baseL >> 6;           // 0..63
  const int scol = (baseL & 63) >> 1;    // elems 0/8/16/24
  const size_t sA = (size_t)(tm + srow) * 4096 + scol;
  const size_t sB = (size_t)(tn + srow) * 4096 + scol;
  const int dOff = tid * 16;

  auto STAGE_A = [&](const u16* g, int ubase, int tau) {  // 256 rows, 4 instr
    if (tau >= 128) return;
    const u16* src = g + sA + (size_t)tau * 32;
    char* lds = SM + ubase + dOff;
#pragma unroll
    for (int q = 0; q < 4; ++q)
      GLDS16(src + (size_t)q * 64 * 4096, lds + q * 4096);
  };
  auto STAGE_B = [&](const u16* g, int ubase, int tau) {  // 128 rows, 2 instr
    if (tau >= 128) return;
    const u16* src = g + sB + (size_t)tau * 32;
    char* lds = SM + ubase + dOff;
    GLDS16(src, lds);
    GLDS16(src + (size_t)64 * 4096, lds + 4096);
  };

  const int slot16 = ((((l15 & 1) << 2) | kslc) ^ (l15 >> 1)) << 4;
  const int aOff = wm * 8192 + (l15 >> 1) * 128 + slot16;
  const int bOff = wn * 4096 + (l15 >> 1) * 128 + slot16;

#define LDSF(ubase, off, f)                                              \
  (*reinterpret_cast<const bfrag*>(SM + (ubase) + (off) + (f) * 1024))

  ffrag acc[8][4];
#pragma unroll
  for (int m = 0; m < 8; ++m)
#pragma unroll
    for (int n = 0; n < 4; ++n) acc[m][n] = {0.f, 0.f, 0.f, 0.f};

  bfrag Ahf[8], Alf[4], Bhf[4], Blf[4];

  // prologue: stage tile 0 (12 instr); Ah,Al,Bh landed; Bl stays in flight
  STAGE_A(Ah_, 0, 0); STAGE_A(Al_, 16384, 0);
  STAGE_B(Bh_, 32768, 0); STAGE_B(Bl_, 40960, 0);
  asm volatile("s_waitcnt vmcnt(2)" ::: "memory");
  MEMFENCE();
  __builtin_amdgcn_s_barrier();

#define MFMA16(Aset, a0, Bset, mb)                                       \
  __builtin_amdgcn_s_setprio(1);                                         \
  _Pragma("unroll")                                                      \
  for (int m = 0; m < 4; ++m)                                            \
    _Pragma("unroll")                                                    \
    for (int n = 0; n < 4; ++n)                                          \
      acc[(mb) + m][n] = __builtin_amdgcn_mfma_f32_16x16x32_bf16(        \
          Aset[(a0) + m], Bset[n], acc[(mb) + m][n], 0, 0, 0);           \
  __builtin_amdgcn_s_setprio(0);

  for (int t = 0; t < 128; ++t) {
    // ---- P0: read Ah[0-3], Bh; MFMA hh m0-3
#pragma unroll
    for (int f = 0; f < 4; ++f) Ahf[f] = LDSF(0, aOff, f);
#pragma unroll
    for (int f = 0; f < 4; ++f) Bhf[f] = LDSF(32768, bOff, f);
    MEMFENCE();
    __builtin_amdgcn_s_barrier();
    MFMA16(Ahf, 0, Bhf, 0)
    MEMFENCE();
    __builtin_amdgcn_s_barrier();
    // ---- P1: read Ah[4-7]; drain+bar; STAGE Ah[t+1]; MFMA hh m4-7
#pragma unroll
    for (int f = 0; f < 4; ++f) Ahf[4 + f] = LDSF(0, aOff, 4 + f);
    asm volatile("s_waitcnt lgkmcnt(0)" ::: "memory");
    MEMFENCE();
    __builtin_amdgcn_s_barrier();
    STAGE_A(Ah_, 0, t + 1);
    MFMA16(Ahf, 4, Bhf, 4)
    MEMFENCE();
    __builtin_amdgcn_s_barrier();
    // ---- P2: read Al[0-3]; MFMA lh m0-3
#pragma unroll
    for (int f = 0; f < 4; ++f) Alf[f] = LDSF(16384, aOff, f);
    MEMFENCE();
    __builtin_amdgcn_s_barrier();
    MFMA16(Alf, 0, Bhf, 0)
    MEMFENCE();
    __builtin_amdgcn_s_barrier();
    // ---- P3: read Al[4-7]; drain+bar; STAGE Al,Bh[t+1]; MFMA lh m4-7;
    //      counted drain of Bl[t]
#pragma unroll
    for (int f = 0; f < 4; ++f) Alf[f] = LDSF(16384, aOff, 4 + f);
    asm volatile("s_waitcnt lgkmcnt(0)" ::: "memory");
    MEMFENCE();
    __builtin_amdgcn_s_barrier();
    STAGE_A(Al_, 16384, t + 1);
    STAGE_B(Bh_, 32768, t + 1);
    MFMA16(Alf, 0, Bhf, 4)
    if (t < 127)
      asm volatile("s_waitcnt vmcnt(10)" ::: "memory");  // Bl[t] landed
    else
      asm volatile("s_waitcnt vmcnt(0)" ::: "memory");   // tail
    MEMFENCE();
    __builtin_amdgcn_s_barrier();
    // ---- P4: read Bl; drain+bar; STAGE Bl[t+1]; MFMA hl (Ah reg-reuse);
    //      tile-end counted wait
#pragma unroll
    for (int f = 0; f < 4; ++f) Blf[f] = LDSF(40960, bOff, f);
    asm volatile("s_waitcnt lgkmcnt(0)" ::: "memory");
    MEMFENCE();
    __builtin_amdgcn_s_barrier();
    STAGE_B(Bl_, 40960, t + 1);
    MFMA16(Ahf, 0, Blf, 0)
    MFMA16(Ahf, 4, Blf, 4)
    asm volatile("s_waitcnt vmcnt(2)" ::: "memory");
    MEMFENCE();
    __builtin_amdgcn_s_barrier();
  }

  // quant epilogue; C/D mapping: col = lane&15, row = (lane>>4)*4 + reg
  const int r0 = tm + wm * 128 + kslc * 4;
  const int c0 = tn + wn * 64 + l15;
#pragma unroll
  for (int m = 0; m < 8; ++m)
#pragma unroll
    for (int n = 0; n < 4; ++n)
#pragma unroll
      for (int r = 0; r < 4; ++r) {
        float y = acc[m][n][r];
        float s = rintf((y + 1.0f) * 7.5f);  // RNE == jnp.round
        int idx = (int)s;
        idx = idx < 0 ? 0 : (idx > 15 ? 15 : idx);
        Yq[(size_t)(r0 + m * 16 + r) * N + (c0 + n * 16)] = f2bf(clut[idx]);
      }
#undef MFMA16
#undef LDSF
}

// ============ GEMM2 (R10 4-phase template VERBATIM, known-good ~195us):
//   out = yq @ Pi   (B^T form via piT)
__global__ void __launch_bounds__(512, 2) gemm256_bt_kernel(
    const u16* __restrict__ A0, const u16* __restrict__ B0,
    float* __restrict__ Cout, int M, int N) {
  constexpr int NT = 64;
  __shared__ __align__(16) char SM[131072];
  const int tid = threadIdx.x;

  const int nbn = N >> 8;
  const int nwg = (M >> 8) * nbn;
  int wg = blockIdx.x;
  wg = (wg & 7) * (nwg >> 3) + (wg >> 3);
  const int tm = (wg / nbn) << 8;
  const int tn = (wg % nbn) << 8;

  const int lane = tid & 63;
  const int wv = tid >> 6;
  const int wm = wv >> 2;
  const int wn = wv & 3;
  const int l15 = lane & 15;
  const int kslc = lane >> 4;
  const int cXor = (lane & 7) << 4;

  const size_t thrOff =
      (size_t)(wv * 8 + (lane >> 3)) * 4096 + 8 * ((lane & 7) ^ (lane >> 3));
  const int ldsThr = wv * 1024 + lane * 16;

  auto STAGE = [&](int kind, int tau) {
    if (tau >= NT) return;
    const int b = tau & 1;
    const size_t ktE = (size_t)tau * 64;
    const u16* src;
    char* lds;
    if (kind >= 2) {
      const int idx = kind - 2;
      src = B0 + (size_t)(tn + idx * 128) * 4096 + ktE + thrOff;
      lds = SM + b * 65536 + 32768 + idx * 16384 + ldsThr;
    } else {
      src = A0 + (size_t)(tm + kind * 128) * 4096 + ktE + thrOff;
      lds = SM + b * 65536 + kind * 16384 + ldsThr;
    }
    GLDS16(src, lds);
    GLDS16(src + 262144, lds + 8192);
  };

#define LDSA(b, f, s)                                                      \
  (*reinterpret_cast<const bfrag*>(                                        \
      SM + (b) * 65536 + wm * 16384 + (((f) * 16 + l15) << 7) +            \
      ((((s) << 6) | (kslc << 4)) ^ cXor)))
#define LDSB(b, f, s)                                                      \
  (*reinterpret_cast<const bfrag*>(                                        \
      SM + (b) * 65536 + 32768 + (wn >> 1) * 16384 +                       \
      ((((wn & 1) * 64) + (f) * 16 + l15) << 7) +                          \
      ((((s) << 6) | (kslc << 4)) ^ cXor)))

  ffrag acc[8][4];
#pragma unroll
  for (int m = 0; m < 8; ++m)
#pragma unroll
    for (int n = 0; n < 4; ++n) acc[m][n] = {0.f, 0.f, 0.f, 0.f};

  STAGE(0, 0); STAGE(1, 0); STAGE(2, 0); STAGE(3, 0);
  STAGE(2, 1); STAGE(3, 1);
  asm volatile("s_waitcnt vmcnt(4)" ::: "memory");
  MEMFENCE();
  __builtin_amdgcn_s_barrier();

  bfrag Af[4], Bf[4];

  for (int t = 0; t < NT; ++t) {
    const int b = t & 1;
#pragma unroll
    for (int p = 0; p < 4; ++p) {
      const int s = p >> 1;
      const int mb = (p & 1) * 4;
      if ((p & 1) == 0) {
#pragma unroll
        for (int n = 0; n < 4; ++n) Bf[n] = LDSB(b, n, s);
      }
#pragma unroll
      for (int m = 0; m < 4; ++m) Af[m] = LDSA(b, mb + m, s);
      if (p == 0) STAGE(0, t + 1);
      else if (p == 1) STAGE(1, t + 1);
      else if (p == 3) { STAGE(2, t + 2); STAGE(3, t + 2); }
      MEMFENCE();
      __builtin_amdgcn_s_barrier();
      asm volatile("s_waitcnt lgkmcnt(0)" ::: "memory");
      __builtin_amdgcn_s_setprio(1);
#pragma unroll
      for (int m = 0; m < 4; ++m)
#pragma unroll
        for (int n = 0; n < 4; ++n)
          acc[mb + m][n] = __builtin_amdgcn_mfma_f32_16x16x32_bf16(
              Af[m], Bf[n], acc[mb + m][n], 0, 0, 0);
      __builtin_amdgcn_s_setprio(0);
      if (p == 3) {
        if (t == NT - 2)
          asm volatile("s_waitcnt vmcnt(0)" ::: "memory");
        else if (t < NT - 2)
          asm volatile("s_waitcnt vmcnt(4)" ::: "memory");
      }
      MEMFENCE();
      __builtin_amdgcn_s_barrier();
    }
  }

  const int r0 = tm + wm * 128 + kslc * 4;
  const int c0 = tn + wn * 64 + l15;
#pragma unroll
  for (int m = 0; m < 8; ++m)
#pragma unroll
    for (int n = 0; n < 4; ++n)
#pragma unroll
      for (int r = 0; r < 4; ++r)
        Cout[(size_t)(r0 + m * 16 + r) * N + (c0 + n * 16)] = acc[m][n][r];
#undef LDSA
#undef LDSB
}

extern "C" void kernel_launch(void* const* d_in, const int* in_sizes, int n_in,
                              void* d_out, int out_size, void* d_ws, size_t ws_size,
                              hipStream_t stream) {
  const float* x = (const float*)d_in[0];     // [8192][4096]
  const float* Pi = (const float*)d_in[1];    // [4096][4096]
  const float* cent = (const float*)d_in[2];  // [16]
  float* out = (float*)d_out;                 // [8192][4096]

  const size_t MB = (size_t)1 << 20;
  if (ws_size < 288 * MB) return;

  char* ws = (char*)d_ws;
  u16* x_hi = (u16*)(ws + 0 * MB);    // 64MB  bf16(x)
  u16* x_lo = (u16*)(ws + 64 * MB);   // 64MB  bf16(x - x_hi)
  u16* p_hi = (u16*)(ws + 128 * MB);  // 32MB  bf16(Pi)
  u16* p_lo = (u16*)(ws + 160 * MB);  // 32MB  bf16(Pi - p_hi)
  u16* piT  = (u16*)(ws + 192 * MB);  // 32MB  bf16(Pi^T)
  u16* yq   = (u16*)(ws + 224 * MB);  // 64MB  bf16(quantize(x @ Pi^T))

  split_bf16_kernel<<<2048, 256, 0, stream>>>(x, x_hi, x_lo, (long)NTOK * DD / 4);
  prep_pi_fused_kernel<<<dim3(DD / 64, DD / 64), 256, 0, stream>>>(
      Pi, p_hi, p_lo, piT);

  // GEMM1 fused 3-term (16x16, 3-blocks/CU) + quantize -> yq
  gemm_fused3_kernel<<<1024, 256, 0, stream>>>(
      x_hi, x_lo, p_hi, p_lo, yq, cent, NTOK, DD);
  // GEMM2 (R10 4-phase template): out = yq @ Pi
  gemm256_bt_kernel<<<512, 512, 0, stream>>>(yq, piT, out, NTOK, DD);
}

// Round 13
// 998.017 us; speedup vs baseline: 4.6624x; 4.6624x over previous
//
#include <hip/hip_runtime.h>
#include <hip/hip_bf16.h>

#define DD 4096
#define NTOK 8192

using u16 = unsigned short;

typedef __attribute__((ext_vector_type(8))) short bfrag;   // 8 bf16 = 4 VGPR
typedef __attribute__((ext_vector_type(4))) float ffrag;   // 16x16 MFMA C/D
typedef __attribute__((ext_vector_type(4))) float f32x4v;

// RNE float -> bf16 (bit math; matches numpy/JAX round-to-nearest-even)
__device__ __forceinline__ u16 f2bf(float f) {
  unsigned u = __float_as_uint(f);
  u += 0x7FFFu + ((u >> 16) & 1u);
  return (u16)(u >> 16);
}
__device__ __forceinline__ float bf2f(u16 u) {
  return __uint_as_float(((unsigned)u) << 16);
}

#define GLDS16(g, l)                                                  \
  __builtin_amdgcn_global_load_lds(                                   \
      (__attribute__((address_space(1))) const void*)(g),             \
      (__attribute__((address_space(3))) void*)(l), 16, 0, 0)

#define MEMFENCE() asm volatile("" ::: "memory")

// ---------------- split x: f32 -> (bf16 hi, bf16 lo) ----------------
__global__ void __launch_bounds__(256) split_bf16_kernel(
    const float* __restrict__ in, u16* __restrict__ hi,
    u16* __restrict__ lo, long n4) {
  long i = (long)blockIdx.x * blockDim.x + threadIdx.x;
  const long stride = (long)gridDim.x * blockDim.x;
  for (; i < n4; i += stride) {
    f32x4v v = reinterpret_cast<const f32x4v*>(in)[i];
    u16 h[4], l[4];
#pragma unroll
    for (int j = 0; j < 4; ++j) {
      float f = v[j];
      u16 hb = f2bf(f);
      h[j] = hb;
      l[j] = f2bf(f - bf2f(hb));
    }
    ushort4 hv, lv;
    hv.x = h[0]; hv.y = h[1]; hv.z = h[2]; hv.w = h[3];
    lv.x = l[0]; lv.y = l[1]; lv.z = l[2]; lv.w = l[3];
    reinterpret_cast<ushort4*>(hi)[i] = hv;
    reinterpret_cast<ushort4*>(lo)[i] = lv;
  }
}

// ------ fused Pi prep: f32 Pi -> p_hi, p_lo (row-major) + piT (bf16 Pi^T)
__global__ void __launch_bounds__(256) prep_pi_fused_kernel(
    const float* __restrict__ in, u16* __restrict__ hi,
    u16* __restrict__ lo, u16* __restrict__ piT) {
  __shared__ u16 tile[64][65];
  const int bc = blockIdx.x << 6;
  const int br = blockIdx.y << 6;
  const int tc = threadIdx.x & 63;
  const int tr0 = threadIdx.x >> 6;
#pragma unroll
  for (int p = 0; p < 16; ++p) {
    int r = tr0 + (p << 2);
    float f = in[(size_t)(br + r) * DD + (bc + tc)];
    u16 hb = f2bf(f);
    hi[(size_t)(br + r) * DD + (bc + tc)] = hb;
    lo[(size_t)(br + r) * DD + (bc + tc)] = f2bf(f - bf2f(hb));
    tile[tc][r] = hb;
  }
  __syncthreads();
#pragma unroll
  for (int p = 0; p < 16; ++p) {
    int orow = tr0 + (p << 2);
    piT[(size_t)(bc + orow) * DD + (br + tc)] = tile[orow][tc];
  }
}

// ============ FUSED 3-term GEMM1 (R10 VERBATIM, 2 blocks/CU — the verified
// optimum):  yq = quant( xh@ph^T + xl@ph^T + xh@pl^T )
// Tile 256x128, 4 waves (2Mx2N), per-wave 128x64. LDS single-buffered 48KB.
// NOTE: acc[8][4] = 128 f32 lives in the unified VGPR/AGPR file -> true
// per-wave footprint ~244 regs -> 2 waves/SIMD is the occupancy CEILING.
// __launch_bounds__(256,3) forces allocator below the acc footprint and
// spills acc to scratch (R12: 8.3GB scratch writes, 6.7x slower). Keep (256,2).
__global__ void __launch_bounds__(256, 2) gemm_fused3_kernel(
    const u16* __restrict__ Ah_, const u16* __restrict__ Al_,
    const u16* __restrict__ Bh_, const u16* __restrict__ Bl_,
    u16* __restrict__ Yq, const float* __restrict__ cent, int M, int N) {
  __shared__ __align__(16) char SM[49152];
  __shared__ float clut[16];
  const int tid = threadIdx.x;
  if (tid < 16) clut[tid] = cent[tid];

  // XCD swizzle (nwg=1024, %8==0 -> bijective)
  const int nbn = N >> 7;                 // 32
  const int nwg = (M >> 8) * nbn;         // 1024
  int wg = blockIdx.x;
  wg = (wg & 7) * (nwg >> 3) + (wg >> 3);
  const int tm = (wg / nbn) << 8;
  const int tn = (wg % nbn) << 7;

  const int lane = tid & 63;
  const int wv = tid >> 6;   // 0..3
  const int wm = wv >> 1;    // 0..1 (128-row panel)
  const int wn = wv & 1;     // 0..1 (64-col panel)
  const int l15 = lane & 15;
  const int kslc = lane >> 4;

  // staging: dest linear, source pre-unswizzled (involution)
  const int key = (tid >> 3) & 7;
  const int baseL = (tid * 16) ^ (key << 4);
  const int srow = baseL >> 6;           // 0..63
  const int scol = (baseL & 63) >> 1;    // elems 0/8/16/24
  const size_t sA = (size_t)(tm + srow) * 4096 + scol;
  const size_t sB = (size_t)(tn + srow) * 4096 + scol;
  const int dOff = tid * 16;

  auto STAGE_A = [&](const u16* g, int ubase, int tau) {  // 256 rows, 4 instr
    if (tau >= 128) return;
    const u16* src = g + sA + (size_t)tau * 32;
    char* lds = SM + ubase + dOff;
#pragma unroll
    for (int q = 0; q < 4; ++q)
      GLDS16(src + (size_t)q * 64 * 4096, lds + q * 4096);
  };
  auto STAGE_B = [&](const u16* g, int ubase, int tau) {  // 128 rows, 2 instr
    if (tau >= 128) return;
    const u16* src = g + sB + (size_t)tau * 32;
    char* lds = SM + ubase + dOff;
    GLDS16(src, lds);
    GLDS16(src + (size_t)64 * 4096, lds + 4096);
  };

  const int slot16 = ((((l15 & 1) << 2) | kslc) ^ (l15 >> 1)) << 4;
  const int aOff = wm * 8192 + (l15 >> 1) * 128 + slot16;
  const int bOff = wn * 4096 + (l15 >> 1) * 128 + slot16;

#define LDSF(ubase, off, f)                                              \
  (*reinterpret_cast<const bfrag*>(SM + (ubase) + (off) + (f) * 1024))

  ffrag acc[8][4];
#pragma unroll
  for (int m = 0; m < 8; ++m)
#pragma unroll
    for (int n = 0; n < 4; ++n) acc[m][n] = {0.f, 0.f, 0.f, 0.f};

  bfrag Ahf[8], Alf[4], Bhf[4], Blf[4];

  // prologue: stage tile 0 (12 instr); Ah,Al,Bh landed; Bl stays in flight
  STAGE_A(Ah_, 0, 0); STAGE_A(Al_, 16384, 0);
  STAGE_B(Bh_, 32768, 0); STAGE_B(Bl_, 40960, 0);
  asm volatile("s_waitcnt vmcnt(2)" ::: "memory");
  MEMFENCE();
  __builtin_amdgcn_s_barrier();

#define MFMA16(Aset, a0, Bset, mb)                                       \
  __builtin_amdgcn_s_setprio(1);                                         \
  _Pragma("unroll")                                                      \
  for (int m = 0; m < 4; ++m)                                            \
    _Pragma("unroll")                                                    \
    for (int n = 0; n < 4; ++n)                                          \
      acc[(mb) + m][n] = __builtin_amdgcn_mfma_f32_16x16x32_bf16(        \
          Aset[(a0) + m], Bset[n], acc[(mb) + m][n], 0, 0, 0);           \
  __builtin_amdgcn_s_setprio(0);

  for (int t = 0; t < 128; ++t) {
    // ---- P0: read Ah[0-3], Bh; MFMA hh m0-3
#pragma unroll
    for (int f = 0; f < 4; ++f) Ahf[f] = LDSF(0, aOff, f);
#pragma unroll
    for (int f = 0; f < 4; ++f) Bhf[f] = LDSF(32768, bOff, f);
    MEMFENCE();
    __builtin_amdgcn_s_barrier();
    MFMA16(Ahf, 0, Bhf, 0)
    MEMFENCE();
    __builtin_amdgcn_s_barrier();
    // ---- P1: read Ah[4-7]; drain+bar; STAGE Ah[t+1]; MFMA hh m4-7
#pragma unroll
    for (int f = 0; f < 4; ++f) Ahf[4 + f] = LDSF(0, aOff, 4 + f);
    asm volatile("s_waitcnt lgkmcnt(0)" ::: "memory");
    MEMFENCE();
    __builtin_amdgcn_s_barrier();
    STAGE_A(Ah_, 0, t + 1);
    MFMA16(Ahf, 4, Bhf, 4)
    MEMFENCE();
    __builtin_amdgcn_s_barrier();
    // ---- P2: read Al[0-3]; MFMA lh m0-3
#pragma unroll
    for (int f = 0; f < 4; ++f) Alf[f] = LDSF(16384, aOff, f);
    MEMFENCE();
    __builtin_amdgcn_s_barrier();
    MFMA16(Alf, 0, Bhf, 0)
    MEMFENCE();
    __builtin_amdgcn_s_barrier();
    // ---- P3: read Al[4-7]; drain+bar; STAGE Al,Bh[t+1]; MFMA lh m4-7;
    //      counted drain of Bl[t]
#pragma unroll
    for (int f = 0; f < 4; ++f) Alf[f] = LDSF(16384, aOff, 4 + f);
    asm volatile("s_waitcnt lgkmcnt(0)" ::: "memory");
    MEMFENCE();
    __builtin_amdgcn_s_barrier();
    STAGE_A(Al_, 16384, t + 1);
    STAGE_B(Bh_, 32768, t + 1);
    MFMA16(Alf, 0, Bhf, 4)
    if (t < 127)
      asm volatile("s_waitcnt vmcnt(10)" ::: "memory");  // Bl[t] landed
    else
      asm volatile("s_waitcnt vmcnt(0)" ::: "memory");   // tail
    MEMFENCE();
    __builtin_amdgcn_s_barrier();
    // ---- P4: read Bl; drain+bar; STAGE Bl[t+1]; MFMA hl (Ah reg-reuse);
    //      tile-end counted wait
#pragma unroll
    for (int f = 0; f < 4; ++f) Blf[f] = LDSF(40960, bOff, f);
    asm volatile("s_waitcnt lgkmcnt(0)" ::: "memory");
    MEMFENCE();
    __builtin_amdgcn_s_barrier();
    STAGE_B(Bl_, 40960, t + 1);
    MFMA16(Ahf, 0, Blf, 0)
    MFMA16(Ahf, 4, Blf, 4)
    asm volatile("s_waitcnt vmcnt(2)" ::: "memory");
    MEMFENCE();
    __builtin_amdgcn_s_barrier();
  }

  // quant epilogue; C/D mapping: col = lane&15, row = (lane>>4)*4 + reg
  const int r0 = tm + wm * 128 + kslc * 4;
  const int c0 = tn + wn * 64 + l15;
#pragma unroll
  for (int m = 0; m < 8; ++m)
#pragma unroll
    for (int n = 0; n < 4; ++n)
#pragma unroll
      for (int r = 0; r < 4; ++r) {
        float y = acc[m][n][r];
        float s = rintf((y + 1.0f) * 7.5f);  // RNE == jnp.round
        int idx = (int)s;
        idx = idx < 0 ? 0 : (idx > 15 ? 15 : idx);
        Yq[(size_t)(r0 + m * 16 + r) * N + (c0 + n * 16)] = f2bf(clut[idx]);
      }
#undef MFMA16
#undef LDSF
}

// ============ GEMM2 (R10 4-phase template VERBATIM, known-good ~195us):
//   out = yq @ Pi   (B^T form via piT)
__global__ void __launch_bounds__(512, 2) gemm256_bt_kernel(
    const u16* __restrict__ A0, const u16* __restrict__ B0,
    float* __restrict__ Cout, int M, int N) {
  constexpr int NT = 64;
  __shared__ __align__(16) char SM[131072];
  const int tid = threadIdx.x;

  const int nbn = N >> 8;
  const int nwg = (M >> 8) * nbn;
  int wg = blockIdx.x;
  wg = (wg & 7) * (nwg >> 3) + (wg >> 3);
  const int tm = (wg / nbn) << 8;
  const int tn = (wg % nbn) << 8;

  const int lane = tid & 63;
  const int wv = tid >> 6;
  const int wm = wv >> 2;
  const int wn = wv & 3;
  const int l15 = lane & 15;
  const int kslc = lane >> 4;
  const int cXor = (lane & 7) << 4;

  const size_t thrOff =
      (size_t)(wv * 8 + (lane >> 3)) * 4096 + 8 * ((lane & 7) ^ (lane >> 3));
  const int ldsThr = wv * 1024 + lane * 16;

  auto STAGE = [&](int kind, int tau) {
    if (tau >= NT) return;
    const int b = tau & 1;
    const size_t ktE = (size_t)tau * 64;
    const u16* src;
    char* lds;
    if (kind >= 2) {
      const int idx = kind - 2;
      src = B0 + (size_t)(tn + idx * 128) * 4096 + ktE + thrOff;
      lds = SM + b * 65536 + 32768 + idx * 16384 + ldsThr;
    } else {
      src = A0 + (size_t)(tm + kind * 128) * 4096 + ktE + thrOff;
      lds = SM + b * 65536 + kind * 16384 + ldsThr;
    }
    GLDS16(src, lds);
    GLDS16(src + 262144, lds + 8192);
  };

#define LDSA(b, f, s)                                                      \
  (*reinterpret_cast<const bfrag*>(                                        \
      SM + (b) * 65536 + wm * 16384 + (((f) * 16 + l15) << 7) +            \
      ((((s) << 6) | (kslc << 4)) ^ cXor)))
#define LDSB(b, f, s)                                                      \
  (*reinterpret_cast<const bfrag*>(                                        \
      SM + (b) * 65536 + 32768 + (wn >> 1) * 16384 +                       \
      ((((wn & 1) * 64) + (f) * 16 + l15) << 7) +                          \
      ((((s) << 6) | (kslc << 4)) ^ cXor)))

  ffrag acc[8][4];
#pragma unroll
  for (int m = 0; m < 8; ++m)
#pragma unroll
    for (int n = 0; n < 4; ++n) acc[m][n] = {0.f, 0.f, 0.f, 0.f};

  STAGE(0, 0); STAGE(1, 0); STAGE(2, 0); STAGE(3, 0);
  STAGE(2, 1); STAGE(3, 1);
  asm volatile("s_waitcnt vmcnt(4)" ::: "memory");
  MEMFENCE();
  __builtin_amdgcn_s_barrier();

  bfrag Af[4], Bf[4];

  for (int t = 0; t < NT; ++t) {
    const int b = t & 1;
#pragma unroll
    for (int p = 0; p < 4; ++p) {
      const int s = p >> 1;
      const int mb = (p & 1) * 4;
      if ((p & 1) == 0) {
#pragma unroll
        for (int n = 0; n < 4; ++n) Bf[n] = LDSB(b, n, s);
      }
#pragma unroll
      for (int m = 0; m < 4; ++m) Af[m] = LDSA(b, mb + m, s);
      if (p == 0) STAGE(0, t + 1);
      else if (p == 1) STAGE(1, t + 1);
      else if (p == 3) { STAGE(2, t + 2); STAGE(3, t + 2); }
      MEMFENCE();
      __builtin_amdgcn_s_barrier();
      asm volatile("s_waitcnt lgkmcnt(0)" ::: "memory");
      __builtin_amdgcn_s_setprio(1);
#pragma unroll
      for (int m = 0; m < 4; ++m)
#pragma unroll
        for (int n = 0; n < 4; ++n)
          acc[mb + m][n] = __builtin_amdgcn_mfma_f32_16x16x32_bf16(
              Af[m], Bf[n], acc[mb + m][n], 0, 0, 0);
      __builtin_amdgcn_s_setprio(0);
      if (p == 3) {
        if (t == NT - 2)
          asm volatile("s_waitcnt vmcnt(0)" ::: "memory");
        else if (t < NT - 2)
          asm volatile("s_waitcnt vmcnt(4)" ::: "memory");
      }
      MEMFENCE();
      __builtin_amdgcn_s_barrier();
    }
  }

  const int r0 = tm + wm * 128 + kslc * 4;
  const int c0 = tn + wn * 64 + l15;
#pragma unroll
  for (int m = 0; m < 8; ++m)
#pragma unroll
    for (int n = 0; n < 4; ++n)
#pragma unroll
      for (int r = 0; r < 4; ++r)
        Cout[(size_t)(r0 + m * 16 + r) * N + (c0 + n * 16)] = acc[m][n][r];
#undef LDSA
#undef LDSB
}

extern "C" void kernel_launch(void* const* d_in, const int* in_sizes, int n_in,
                              void* d_out, int out_size, void* d_ws, size_t ws_size,
                              hipStream_t stream) {
  const float* x = (const float*)d_in[0];     // [8192][4096]
  const float* Pi = (const float*)d_in[1];    // [4096][4096]
  const float* cent = (const float*)d_in[2];  // [16]
  float* out = (float*)d_out;                 // [8192][4096]

  const size_t MB = (size_t)1 << 20;
  if (ws_size < 288 * MB) return;

  char* ws = (char*)d_ws;
  u16* x_hi = (u16*)(ws + 0 * MB);    // 64MB  bf16(x)
  u16* x_lo = (u16*)(ws + 64 * MB);   // 64MB  bf16(x - x_hi)
  u16* p_hi = (u16*)(ws + 128 * MB);  // 32MB  bf16(Pi)
  u16* p_lo = (u16*)(ws + 160 * MB);  // 32MB  bf16(Pi - p_hi)
  u16* piT  = (u16*)(ws + 192 * MB);  // 32MB  bf16(Pi^T)
  u16* yq   = (u16*)(ws + 224 * MB);  // 64MB  bf16(quantize(x @ Pi^T))

  split_bf16_kernel<<<2048, 256, 0, stream>>>(x, x_hi, x_lo, (long)NTOK * DD / 4);
  prep_pi_fused_kernel<<<dim3(DD / 64, DD / 64), 256, 0, stream>>>(
      Pi, p_hi, p_lo, piT);

  // GEMM1 fused 3-term (16x16, 2-blocks/CU) + quantize -> yq
  gemm_fused3_kernel<<<1024, 256, 0, stream>>>(
      x_hi, x_lo, p_hi, p_lo, yq, cent, NTOK, DD);
  // GEMM2 (R10 4-phase template): out = yq @ Pi
  gemm256_bt_kernel<<<512, 512, 0, stream>>>(yq, piT, out, NTOK, DD);
}